// Round 7
// baseline (233.584 us; speedup 1.0000x reference)
//
#include <hip/hip_runtime.h>
#include <stdint.h>
#include <stddef.h>

#define N_SENT 100000
#define N_TYPE 10000
#define NEDGE  640000
#define NROWS  (N_SENT + N_TYPE)
#define HB     64            // histogram chunks; 64 * 10000 == NEDGE exactly
#define HCHUNK (NEDGE / HB)
#define NSLAB  8
#define SLABW  (N_SENT / NSLAB)   // 12500 rows = 3.2 MB bf16, fits one XCD L2

__device__ __forceinline__ float bf2f(uint32_t lo16) {
    return __builtin_bit_cast(float, lo16 << 16);
}
__device__ __forceinline__ uint32_t f2bf(float f) {
    uint32_t u = __builtin_bit_cast(uint32_t, f);
    return (u + 0x7fffu + ((u >> 16) & 1u)) >> 16;
}

// Inline per-wave dtype probe: bf16 pairs have bf16-sane exponents in the low halfword;
// f32 low halfwords are mantissa bits (uniform). One broadcast load + ballot, wave-uniform.
__device__ __forceinline__ bool detect_bf16(const uint32_t* __restrict__ h) {
    uint32_t u = h[threadIdx.x & 63];
    uint32_t e_lo = (u >> 7) & 0xffu;
    int ok = (e_lo >= 100u && e_lo <= 140u) ? 1 : 0;
    unsigned long long m = __ballot(ok);
    return __popcll(m) >= 48;
}

// ---- scores: 16 rows per wave, 64 rows per block ----
#define SCORE_BLOCKS ((NROWS + 63) / 64)   // 1719

__global__ __launch_bounds__(256) void scores_k(const void* __restrict__ h_sent,
                                                const void* __restrict__ h_type,
                                                const void* __restrict__ attn_w,
                                                float* __restrict__ s_src,
                                                float* __restrict__ s_dst) {
    int lane = threadIdx.x & 63;
    int r0   = (blockIdx.x * 4 + (int)(threadIdx.x >> 6)) * 16;  // first of 16 rows
    bool isbf = detect_bf16((const uint32_t*)h_sent);
    float v[16];
    if (isbf) {
        uint32_t wv_s = ((const uint32_t*)attn_w)[lane];
        uint32_t wv_t = ((const uint32_t*)attn_w)[64 + lane];
        float ws0 = bf2f(wv_s & 0xffffu), ws1 = bf2f(wv_s >> 16);
        float wt0 = bf2f(wv_t & 0xffffu), wt1 = bf2f(wv_t >> 16);
#pragma unroll
        for (int i = 0; i < 16; i++) {
            int g = r0 + i;
            if (g >= NROWS) { v[i] = 0.0f; continue; }
            bool isSrc = g < N_SENT;
            const uint32_t* hp = isSrc
                ? (const uint32_t*)h_sent + (size_t)g * 64
                : (const uint32_t*)h_type + (size_t)(g - N_SENT) * 64;
            uint32_t hv = hp[lane];
            v[i] = isSrc ? (bf2f(hv & 0xffffu) * ws0 + bf2f(hv >> 16) * ws1)
                         : (bf2f(hv & 0xffffu) * wt0 + bf2f(hv >> 16) * wt1);
        }
    } else {
        float2 wv_s = ((const float2*)attn_w)[lane];
        float2 wv_t = ((const float2*)attn_w)[64 + lane];
#pragma unroll
        for (int i = 0; i < 16; i++) {
            int g = r0 + i;
            if (g >= NROWS) { v[i] = 0.0f; continue; }
            bool isSrc = g < N_SENT;
            const float2* hp = isSrc
                ? (const float2*)h_sent + (size_t)g * 64
                : (const float2*)h_type + (size_t)(g - N_SENT) * 64;
            float2 hv = hp[lane];
            v[i] = isSrc ? (hv.x * wv_s.x + hv.y * wv_s.y)
                         : (hv.x * wv_t.x + hv.y * wv_t.y);
        }
    }
    // fold 16 rows -> 1 value/lane (row = lane&15): merge d=1,2,4,8 then butterfly
    int b0 = lane & 1, b1 = (lane >> 1) & 1, b2 = (lane >> 2) & 1, b3 = (lane >> 3) & 1;
    float w_[8];
#pragma unroll
    for (int i = 0; i < 8; i++) {
        float keep = b0 ? v[2 * i + 1] : v[2 * i];
        float send = b0 ? v[2 * i]     : v[2 * i + 1];
        w_[i] = keep + __shfl_xor(send, 1, 64);
    }
    float x_[4];
#pragma unroll
    for (int i = 0; i < 4; i++) {
        float keep = b1 ? w_[2 * i + 1] : w_[2 * i];
        float send = b1 ? w_[2 * i]     : w_[2 * i + 1];
        x_[i] = keep + __shfl_xor(send, 2, 64);
    }
    float y_[2];
#pragma unroll
    for (int i = 0; i < 2; i++) {
        float keep = b2 ? x_[2 * i + 1] : x_[2 * i];
        float send = b2 ? x_[2 * i]     : x_[2 * i + 1];
        y_[i] = keep + __shfl_xor(send, 4, 64);
    }
    float z;
    {
        float keep = b3 ? y_[1] : y_[0];
        float send = b3 ? y_[0] : y_[1];
        z = keep + __shfl_xor(send, 8, 64);
    }
    z += __shfl_xor(z, 16, 64);
    z += __shfl_xor(z, 32, 64);
    if (lane < 16) {
        int g = r0 + lane;
        if (g < NROWS) {
            if (g < N_SENT) s_src[g] = z;
            else            s_dst[g - N_SENT] = z;
        }
    }
}

// ---- count: per-chunk LDS histogram -> plain stores into count2[c][bin] ----
__global__ __launch_bounds__(256) void count_k(const int* __restrict__ dst,
                                               uint32_t* __restrict__ count2) {
    __shared__ uint32_t hist[N_TYPE];   // 40 KB
    int cb = blockIdx.x;
    int t  = threadIdx.x;
    for (int i = t; i < N_TYPE; i += 256) hist[i] = 0u;
    __syncthreads();
    int e0 = cb * HCHUNK;
    for (int i = t; i < HCHUNK; i += 256)
        atomicAdd(&hist[dst[e0 + i]], 1u);
    __syncthreads();
    uint32_t* row = count2 + (size_t)cb * N_TYPE;
    for (int i = t; i < N_TYPE; i += 256) row[i] = hist[i];
}

// ---- column exclusive-scan over chunks: count2 -> base2 (in place), total[bin] ----
__global__ __launch_bounds__(256) void sumscan_k(uint32_t* __restrict__ count2,
                                                 uint32_t* __restrict__ total) {
    int b = blockIdx.x * 256 + threadIdx.x;
    if (b >= N_TYPE) return;
    uint32_t run = 0;
#pragma unroll 4
    for (int c = 0; c < HB; c++) {
        uint32_t* p = count2 + (size_t)c * N_TYPE + b;
        uint32_t v = *p;
        *p = run;
        run += v;
    }
    total[b] = run;
}

// ---- single-block exclusive scan of totals -> offsets[N_TYPE+1] ----
__global__ __launch_bounds__(1024) void scan_k(const uint32_t* __restrict__ total,
                                               uint32_t* __restrict__ offsets) {
    const int CH = 10;
    int t = threadIdx.x, lane = t & 63, wv = t >> 6;
    int base = t * CH;
    uint32_t local[CH];
    uint32_t tsum = 0;
#pragma unroll
    for (int i = 0; i < CH; i++) {
        int idx = base + i;
        uint32_t c = (idx < N_TYPE) ? total[idx] : 0u;
        local[i] = c;
        tsum += c;
    }
    uint32_t orig = tsum;
#pragma unroll
    for (int off = 1; off < 64; off <<= 1) {
        uint32_t v = __shfl_up(tsum, off, 64);
        if (lane >= off) tsum += v;
    }
    __shared__ uint32_t wsum[16];
    if (lane == 63) wsum[wv] = tsum;
    __syncthreads();
    if (wv == 0 && lane < 16) {
        uint32_t u = wsum[lane], o = u;
#pragma unroll
        for (int off = 1; off < 16; off <<= 1) {
            uint32_t v = __shfl_up(u, off, 64);
            if (lane >= off) u += v;
        }
        wsum[lane] = u - o;
    }
    __syncthreads();
    uint32_t run = wsum[wv] + tsum - orig;
#pragma unroll
    for (int i = 0; i < CH; i++) {
        int idx = base + i;
        if (idx < N_TYPE) {
            offsets[idx] = run;
            run += local[i];
        } else if (idx == N_TYPE) {
            offsets[idx] = run;   // == NEDGE
        }
    }
}

// ---- fill: LDS cursors from offsets+base2; scatter (src, w=exp(lrelu(score))) ----
__global__ __launch_bounds__(256) void fill_k(const int* __restrict__ src,
                                              const int* __restrict__ dst,
                                              const float* __restrict__ s_src,
                                              const float* __restrict__ s_dst,
                                              const uint32_t* __restrict__ offsets,
                                              const uint32_t* __restrict__ base2,
                                              uint2* __restrict__ edata) {
    __shared__ uint32_t cur[N_TYPE];   // 40 KB
    int cb = blockIdx.x;
    int t  = threadIdx.x;
    const uint32_t* brow = base2 + (size_t)cb * N_TYPE;
    for (int i = t; i < N_TYPE; i += 256) cur[i] = offsets[i] + brow[i];
    __syncthreads();
    int e0 = cb * HCHUNK;
    for (int i = t; i < HCHUNK; i += 256) {
        int e = e0 + i;
        int d = dst[e];
        int s = src[e];
        float v = s_src[s] + s_dst[d];
        v = v > 0.0f ? v : 0.01f * v;
        float w = __expf(v);                    // max-free softmax: |v| <~ 6, f32-safe
        uint32_t pos = atomicAdd(&cur[d], 1u);  // LDS-only atomic
        edata[pos] = make_uint2((uint32_t)s, __builtin_bit_cast(uint32_t, w));
    }
}

// ---- slab agg: one wave per (dst, slab). blockIdx&7 = slab -> round-robin XCDs,
//      so slab s's 3.2 MB of h_sent stays resident in XCD s's L2.
__global__ __launch_bounds__(256) void slab_agg_k(const void* __restrict__ h_sent,
                                                  const uint32_t* __restrict__ offsets,
                                                  const uint2* __restrict__ edata,
                                                  uint32_t* __restrict__ pnum,
                                                  float* __restrict__ pden) {
    int lane = threadIdx.x & 63;
    int slab = blockIdx.x & 7;
    int j    = (blockIdx.x >> 3) * 4 + (threadIdx.x >> 6);
    if (j >= N_TYPE) return;
    bool isbf = detect_bf16((const uint32_t*)h_sent);
    uint32_t beg = offsets[j], end = offsets[j + 1];
    uint32_t slo = (uint32_t)slab * SLABW, shi = slo + SLABW;
    const uint32_t* hpb = (const uint32_t*)h_sent;
    const float2*   hpf = (const float2*)h_sent;
    float a0 = 0.0f, a1 = 0.0f, wsum = 0.0f;
    for (uint32_t base = beg; base < end; base += 64) {
        uint32_t k = base + lane;
        uint2 ed = (k < end) ? edata[k] : make_uint2(0u, 0u);
        uint32_t s = ed.x;
        float    w = __builtin_bit_cast(float, ed.y);
        bool act = (k < end) && (s >= slo) && (s < shi);
        float wl = act ? w : 0.0f;
        wsum += wl;
        unsigned long long mask = __ballot(act);   // wave-uniform from here on
        while (mask) {
            int idx[8];
            int cnt = 0;
            while (mask && cnt < 8) { idx[cnt++] = __builtin_ctzll(mask); mask &= mask - 1; }
#pragma unroll
            for (int i = 0; i < 8; i++) if (i >= cnt) idx[i] = 0;
            uint32_t sb[8]; float wb[8];
#pragma unroll
            for (int i = 0; i < 8; i++) {
                sb[i] = __shfl(s,  idx[i], 64);
                wb[i] = (i < cnt) ? __shfl(wl, idx[i], 64) : 0.0f;
            }
            if (isbf) {
                uint32_t gv[8];
#pragma unroll
                for (int i = 0; i < 8; i++) gv[i] = (i < cnt) ? hpb[(size_t)sb[i] * 64 + lane] : 0u;
#pragma unroll
                for (int i = 0; i < 8; i++) {
                    a0 += wb[i] * bf2f(gv[i] & 0xffffu);
                    a1 += wb[i] * bf2f(gv[i] >> 16);
                }
            } else {
                float2 gv[8];
#pragma unroll
                for (int i = 0; i < 8; i++)
                    gv[i] = (i < cnt) ? hpf[(size_t)sb[i] * 64 + lane] : make_float2(0.f, 0.f);
#pragma unroll
                for (int i = 0; i < 8; i++) {
                    a0 += wb[i] * gv[i].x;
                    a1 += wb[i] * gv[i].y;
                }
            }
        }
    }
#pragma unroll
    for (int off = 32; off; off >>= 1) wsum += __shfl_xor(wsum, off, 64);
    uint32_t row = (uint32_t)j * 8 + slab;
    pnum[(size_t)row * 64 + lane] = f2bf(a0) | (f2bf(a1) << 16);
    if (lane == 0) pden[row] = wsum;
}

// ---- combine: sum 8 slab partials per dst, normalize; den==0 -> copy h_type ----
__global__ __launch_bounds__(256) void combine_k(const void* __restrict__ h_type,
                                                 const uint32_t* __restrict__ pnum,
                                                 const float* __restrict__ pden,
                                                 void* __restrict__ out) {
    int lane = threadIdx.x & 63;
    int j = (blockIdx.x * 256 + (int)threadIdx.x) >> 6;
    if (j >= N_TYPE) return;
    bool isbf = detect_bf16((const uint32_t*)h_type);
    float a0 = 0.0f, a1 = 0.0f, den = 0.0f;
#pragma unroll
    for (int s = 0; s < 8; s++) {
        uint32_t row = (uint32_t)j * 8 + s;
        uint32_t v = pnum[(size_t)row * 64 + lane];
        a0 += bf2f(v & 0xffffu);
        a1 += bf2f(v >> 16);
        den += pden[row];
    }
    if (den > 0.0f) {
        float inv = 1.0f / den;
        if (isbf) ((uint32_t*)out)[(size_t)j * 64 + lane] = f2bf(a0 * inv) | (f2bf(a1 * inv) << 16);
        else      ((float2*)out)[(size_t)j * 64 + lane]   = make_float2(a0 * inv, a1 * inv);
    } else {
        if (isbf) ((uint32_t*)out)[(size_t)j * 64 + lane] = ((const uint32_t*)h_type)[(size_t)j * 64 + lane];
        else      ((float2*)out)[(size_t)j * 64 + lane]   = ((const float2*)h_type)[(size_t)j * 64 + lane];
    }
}

// ---- fallback plain agg (ws too small for partials): max-free, register-broadcast ----
__global__ __launch_bounds__(256) void plain_agg_k(const void* __restrict__ h_sent,
                                                   const void* __restrict__ h_type,
                                                   const uint32_t* __restrict__ offsets,
                                                   const uint2* __restrict__ edata,
                                                   void* __restrict__ out) {
    int lane = threadIdx.x & 63;
    int j = (blockIdx.x * 256 + (int)threadIdx.x) >> 6;
    if (j >= N_TYPE) return;
    bool isbf = detect_bf16((const uint32_t*)h_sent);
    uint32_t beg = offsets[j], end = offsets[j + 1];
    if (beg == end) {
        if (isbf) ((uint32_t*)out)[(size_t)j * 64 + lane] = ((const uint32_t*)h_type)[(size_t)j * 64 + lane];
        else      ((float2*)out)[(size_t)j * 64 + lane]   = ((const float2*)h_type)[(size_t)j * 64 + lane];
        return;
    }
    const uint32_t* hpb = (const uint32_t*)h_sent;
    const float2*   hpf = (const float2*)h_sent;
    float a0 = 0.0f, a1 = 0.0f, wsum = 0.0f;
    for (uint32_t base = beg; base < end; base += 64) {
        uint32_t k = base + lane;
        uint2 ed = (k < end) ? edata[k] : make_uint2(0u, 0u);
        uint32_t s = ed.x;
        float    w = (k < end) ? __builtin_bit_cast(float, ed.y) : 0.0f;
        wsum += w;
        int rem = (int)(end - base); if (rem > 64) rem = 64;
        for (int bb = 0; bb < rem; bb += 8) {
            int cnt = rem - bb; if (cnt > 8) cnt = 8;     // wave-uniform
            uint32_t sb[8]; float wb[8];
#pragma unroll
            for (int i = 0; i < 8; i++) {
                sb[i] = __shfl(s, bb + i, 64);
                wb[i] = (i < cnt) ? __shfl(w, bb + i, 64) : 0.0f;
            }
            if (isbf) {
                uint32_t gv[8];
#pragma unroll
                for (int i = 0; i < 8; i++) gv[i] = (i < cnt) ? hpb[(size_t)sb[i] * 64 + lane] : 0u;
#pragma unroll
                for (int i = 0; i < 8; i++) {
                    a0 += wb[i] * bf2f(gv[i] & 0xffffu);
                    a1 += wb[i] * bf2f(gv[i] >> 16);
                }
            } else {
                float2 gv[8];
#pragma unroll
                for (int i = 0; i < 8; i++)
                    gv[i] = (i < cnt) ? hpf[(size_t)sb[i] * 64 + lane] : make_float2(0.f, 0.f);
#pragma unroll
                for (int i = 0; i < 8; i++) {
                    a0 += wb[i] * gv[i].x;
                    a1 += wb[i] * gv[i].y;
                }
            }
        }
    }
#pragma unroll
    for (int off = 32; off; off >>= 1) wsum += __shfl_xor(wsum, off, 64);
    float inv = 1.0f / wsum;
    if (isbf) ((uint32_t*)out)[(size_t)j * 64 + lane] = f2bf(a0 * inv) | (f2bf(a1 * inv) << 16);
    else      ((float2*)out)[(size_t)j * 64 + lane]   = make_float2(a0 * inv, a1 * inv);
}

static inline size_t align_up(size_t x) { return (x + 255) & ~(size_t)255; }

extern "C" void kernel_launch(void* const* d_in, const int* in_sizes, int n_in,
                              void* d_out, int out_size, void* d_ws, size_t ws_size,
                              hipStream_t stream) {
    const void* h_sent = d_in[0];
    const void* h_type = d_in[1];
    const void* attn_w = d_in[2];
    const int* src_idx = (const int*)d_in[3];
    const int* dst_idx = (const int*)d_in[4];

    char* w = (char*)d_ws;
    float*    s_src   = (float*)w;    w += align_up((size_t)N_SENT * 4);
    float*    s_dst   = (float*)w;    w += align_up((size_t)N_TYPE * 4);
    uint32_t* count2  = (uint32_t*)w; w += align_up((size_t)HB * N_TYPE * 4);   // 2.56 MB
    uint32_t* total   = (uint32_t*)w; w += align_up((size_t)N_TYPE * 4);
    uint32_t* offsets = (uint32_t*)w; w += align_up((size_t)(N_TYPE + 1) * 4);
    uint2*    edata   = (uint2*)w;    w += align_up((size_t)NEDGE * 8);         // 5.12 MB
    uint32_t* pnum    = (uint32_t*)w; w += align_up((size_t)N_TYPE * 8 * 64 * 4); // 20.5 MB
    float*    pden    = (float*)w;    w += align_up((size_t)N_TYPE * 8 * 4);
    size_t need_slab = (size_t)(w - (char*)d_ws);
    bool use_slab = ws_size >= need_slab;   // ws_size constant across calls -> same path

    scores_k<<<SCORE_BLOCKS, 256, 0, stream>>>(h_sent, h_type, attn_w, s_src, s_dst);
    count_k<<<HB, 256, 0, stream>>>(dst_idx, count2);
    sumscan_k<<<(N_TYPE + 255) / 256, 256, 0, stream>>>(count2, total);
    scan_k<<<1, 1024, 0, stream>>>(total, offsets);
    fill_k<<<HB, 256, 0, stream>>>(src_idx, dst_idx, s_src, s_dst, offsets, count2, edata);
    if (use_slab) {
        slab_agg_k<<<(N_TYPE / 4) * 8, 256, 0, stream>>>(h_sent, offsets, edata, pnum, pden);
        combine_k<<<(N_TYPE + 3) / 4, 256, 0, stream>>>(h_type, pnum, pden, d_out);
    } else {
        plain_agg_k<<<(N_TYPE + 3) / 4, 256, 0, stream>>>(h_sent, h_type, offsets, edata, d_out);
    }
}